// Round 10
// baseline (442.276 us; speedup 1.0000x reference)
//
#include <hip/hip_runtime.h>
#include <hip/hip_cooperative_groups.h>
#include <hip/hip_bf16.h>
#include <stdint.h>

namespace cg = cooperative_groups;

#define B_   4
#define N_   10000
#define K_   16
#define D_   256
#define OUT_ 256
#define KDIM 512          // 2*D
#define M_   (B_ * N_)    // 40000
#define CW   32           // cols per gather chunk (64 B rows)
#define NCH  8            // number of chunks (one per XCD)
#define GRID 640          // cooperative grid size (2.5 blocks/CU)
#define CHUNK_ELEMS ((size_t)N_ * B_ * CW)   // ushorts per chunk = 1,280,000

typedef __attribute__((ext_vector_type(8))) short          short8;    // MFMA frag
typedef __attribute__((ext_vector_type(8))) unsigned short ushort8;
typedef __attribute__((ext_vector_type(4))) float          f32x4;
typedef __attribute__((ext_vector_type(4))) unsigned short ushort4_t;

__device__ inline unsigned short f2bf(float f) {
    __hip_bfloat16 h = __float2bfloat16(f);
    return *reinterpret_cast<unsigned short*>(&h);
}
__device__ inline float bf2f(unsigned short u) {
    unsigned int v = ((unsigned int)u) << 16;
    return __builtin_bit_cast(float, v);
}

// ===========================================================================
// MEGA: all three stages in one cooperative kernel, grid.sync between phases.
// Phase P: x fp32 -> xc (chunk-major bf16) ; W -> Wb bf16.      (5128 units)
// Phase G: XCD-chunked gather+mean -> hagg.                     (5000 units)
// Phase M: proven bt3 GEMM tile per block (blocks < 625).
// ===========================================================================
__global__ __launch_bounds__(256, 3) void mega(const float* __restrict__ x,
                                               const float* __restrict__ W,
                                               const int*   __restrict__ neigh,
                                               const float* __restrict__ bias,
                                               float*       __restrict__ out,
                                               unsigned short* __restrict__ xc,
                                               unsigned short* __restrict__ hagg,
                                               unsigned short* __restrict__ Wb) {
    cg::grid_group gg = cg::this_grid();
    const int tid = threadIdx.x;
    const int bid = blockIdx.x;

    __shared__ unsigned short As[64 * 32];    //  4 KB (GEMM)
    __shared__ unsigned short Bs[256 * 32];   // 16 KB (GEMM)
    __shared__ int idx_s[256];                //  1 KB (gather)

    // ---------------- Phase P: prep ----------------
    for (int u = bid; u < 5128; u += GRID) {
        if (u < 5000) {
            const int n  = u * 2 + (tid >> 7);
            const int b  = (tid >> 5) & 3;
            const int c0 = (tid & 31) * 8;
            const float4* xr = (const float4*)(x + ((size_t)b * N_ + n) * D_ + c0);
            float4 v0 = xr[0];
            float4 v1 = xr[1];
            ushort8 s;
            s[0] = f2bf(v0.x); s[1] = f2bf(v0.y); s[2] = f2bf(v0.z); s[3] = f2bf(v0.w);
            s[4] = f2bf(v1.x); s[5] = f2bf(v1.y); s[6] = f2bf(v1.z); s[7] = f2bf(v1.w);
            const int ch  = c0 >> 5;
            const int col = c0 & 31;
            *(ushort8*)(xc + (size_t)ch * CHUNK_ELEMS + ((size_t)n * B_ + b) * CW + col) = s;
        } else {
            const int g = (u - 5000) * 256 + tid;      // 0..32767
            float4 v = ((const float4*)W)[g];
            ushort4_t s;
            s.x = f2bf(v.x); s.y = f2bf(v.y); s.z = f2bf(v.z); s.w = f2bf(v.w);
            ((ushort4_t*)Wb)[g] = s;
        }
    }
    __threadfence();
    gg.sync();

    // ---------------- Phase G: gather + mean ----------------
    for (int u = bid; u < 5000; u += GRID) {
        __syncthreads();                                // idx_s reuse guard
        idx_s[tid] = neigh[(u >> 3) * 256 + tid];       // 16 nodes x 16
        __syncthreads();

        const int c  = u & 7;
        const int n0 = (u >> 3) * 16;
        const int q  = tid & 3;
        const int tl = tid >> 2;
        const int ns = tl >> 2;
        const int b  = tl & 3;

        const unsigned short* xcc = xc + (size_t)c * CHUNK_ELEMS;

        int jj[K_];
        int cnt = 0;
#pragma unroll
        for (int k = 0; k < K_; ++k) {
            jj[k] = idx_s[ns * K_ + k];
            cnt += jj[k] >= 0 ? 1 : 0;
        }

        ushort8 vv[K_];
#pragma unroll
        for (int k = 0; k < K_; ++k) {
            const int jc = jj[k] >= 0 ? jj[k] : 0;
            vv[k] = *(const ushort8*)(xcc + ((size_t)jc * B_ + b) * CW + q * 8);
        }

        float acc[8] = {0.f, 0.f, 0.f, 0.f, 0.f, 0.f, 0.f, 0.f};
#pragma unroll
        for (int k = 0; k < K_; ++k) {
            const float m = jj[k] >= 0 ? 1.f : 0.f;
#pragma unroll
            for (int e = 0; e < 8; ++e) acc[e] += bf2f(vv[k][e]) * m;
        }
        const float inv = 1.0f / (float)(cnt > 1 ? cnt : 1);

        ushort8 s;
#pragma unroll
        for (int e = 0; e < 8; ++e) s[e] = f2bf(acc[e] * inv);
        *(ushort8*)(hagg + ((size_t)b * N_ + n0 + ns) * D_ + c * CW + q * 8) = s;
    }
    __threadfence();
    gg.sync();

    // ---------------- Phase M: GEMM (proven bt3 body) ----------------
    if (bid < 625) {
        const int w      = tid >> 6;
        const int lane   = tid & 63;
        const int tile_m = bid * 64;
        const int q      = lane >> 4;
        const int r16    = lane & 15;
        const int crow   = lane >> 2;
        const int kofs   = (lane & 3) * 8;

        const unsigned short* ps[4];
        const unsigned short* pa[4];
#pragma unroll
        for (int c = 0; c < 4; ++c) {
            const int m  = tile_m + c * 16 + crow;
            const int b  = (m >= N_) + (m >= 2 * N_) + (m >= 3 * N_);
            const int n  = m - b * N_;
            ps[c] = xc + ((size_t)n * B_ + b) * CW + kofs;
            pa[c] = hagg + (size_t)m * D_ + kofs;
        }

        f32x4 acc[4][4] = {};

        for (int kk = 0; kk < KDIM; kk += 32) {
            const int kidx = kk >> 5;
#pragma unroll
            for (int t = 0; t < 5; ++t) {
                const int c = w * 5 + t;
                if (c < 4) {
                    const unsigned short* ga = (kk < D_)
                        ? ps[c] + (size_t)kidx * CHUNK_ELEMS
                        : pa[c] + (kk - D_);
                    __builtin_amdgcn_global_load_lds(
                        (const __attribute__((address_space(1))) void*)ga,
                        (__attribute__((address_space(3))) void*)(As + c * 512),
                        16, 0, 0);
                } else {
                    const int row = (c - 4) * 16 + crow;
                    const unsigned short* gb = Wb + (size_t)row * KDIM + kk + kofs;
                    __builtin_amdgcn_global_load_lds(
                        (const __attribute__((address_space(1))) void*)gb,
                        (__attribute__((address_space(3))) void*)(Bs + (c - 4) * 512),
                        16, 0, 0);
                }
            }
            __syncthreads();

            short8 a[4], bf[4];
#pragma unroll
            for (int i = 0; i < 4; ++i)
                a[i] = *(const short8*)(As + (i * 16 + r16) * 32 + q * 8);
#pragma unroll
            for (int j = 0; j < 4; ++j)
                bf[j] = *(const short8*)(Bs + (w * 64 + j * 16 + r16) * 32 + q * 8);

#pragma unroll
            for (int i = 0; i < 4; ++i)
#pragma unroll
                for (int j = 0; j < 4; ++j)
                    acc[i][j] = __builtin_amdgcn_mfma_f32_16x16x32_bf16(a[i], bf[j], acc[i][j], 0, 0, 0);

            __syncthreads();
        }

        float bj[4];
#pragma unroll
        for (int j = 0; j < 4; ++j)
            bj[j] = bias[w * 64 + j * 16 + r16];

#pragma unroll
        for (int i = 0; i < 4; ++i) {
#pragma unroll
            for (int reg = 0; reg < 4; ++reg) {
                const int m = tile_m + i * 16 + q * 4 + reg;
                float* orow = out + (size_t)m * OUT_ + w * 64;
#pragma unroll
                for (int j = 0; j < 4; ++j) {
                    float v = acc[i][j][reg] + bj[j];
                    orow[j * 16 + r16] = v > 0.f ? v : 0.f;
                }
            }
        }
    }
}

// ===========================================================================
// Fallback path: the proven round-9 3-kernel pipeline (launched only if the
// cooperative launch is rejected, e.g. by graph capture).
// ===========================================================================
__global__ __launch_bounds__(256) void prep(const float* __restrict__ x,
                                            const float* __restrict__ W,
                                            unsigned short* __restrict__ xc,
                                            unsigned short* __restrict__ Wb) {
    const int t = threadIdx.x;
    if (blockIdx.x < 5000) {
        const int n  = blockIdx.x * 2 + (t >> 7);
        const int b  = (t >> 5) & 3;
        const int c0 = (t & 31) * 8;
        const float4* xr = (const float4*)(x + ((size_t)b * N_ + n) * D_ + c0);
        float4 v0 = xr[0];
        float4 v1 = xr[1];
        ushort8 s;
        s[0] = f2bf(v0.x); s[1] = f2bf(v0.y); s[2] = f2bf(v0.z); s[3] = f2bf(v0.w);
        s[4] = f2bf(v1.x); s[5] = f2bf(v1.y); s[6] = f2bf(v1.z); s[7] = f2bf(v1.w);
        const int ch  = c0 >> 5;
        const int col = c0 & 31;
        *(ushort8*)(xc + (size_t)ch * CHUNK_ELEMS + ((size_t)n * B_ + b) * CW + col) = s;
    } else {
        int g = (blockIdx.x - 5000) * 256 + t;
        float4 v = ((const float4*)W)[g];
        ushort4_t s;
        s.x = f2bf(v.x); s.y = f2bf(v.y); s.z = f2bf(v.z); s.w = f2bf(v.w);
        ((ushort4_t*)Wb)[g] = s;
    }
}

__global__ __launch_bounds__(256) void gather_agg2(const unsigned short* __restrict__ xc,
                                                   const int*            __restrict__ neigh,
                                                   unsigned short*       __restrict__ hagg) {
    const int c   = blockIdx.x & 7;
    const int g   = blockIdx.x >> 3;
    const int n0  = g * 16;
    const int tid = threadIdx.x;

    __shared__ int idx_s[16 * K_];
    idx_s[tid] = neigh[n0 * K_ + tid];
    __syncthreads();

    const int q  = tid & 3;
    const int tl = tid >> 2;
    const int ns = tl >> 2;
    const int b  = tl & 3;

    const unsigned short* xcc = xc + (size_t)c * CHUNK_ELEMS;

    int jj[K_];
    int cnt = 0;
#pragma unroll
    for (int k = 0; k < K_; ++k) {
        jj[k] = idx_s[ns * K_ + k];
        cnt += jj[k] >= 0 ? 1 : 0;
    }

    ushort8 vv[K_];
#pragma unroll
    for (int k = 0; k < K_; ++k) {
        const int jc = jj[k] >= 0 ? jj[k] : 0;
        vv[k] = *(const ushort8*)(xcc + ((size_t)jc * B_ + b) * CW + q * 8);
    }

    float acc[8] = {0.f, 0.f, 0.f, 0.f, 0.f, 0.f, 0.f, 0.f};
#pragma unroll
    for (int k = 0; k < K_; ++k) {
        const float m = jj[k] >= 0 ? 1.f : 0.f;
#pragma unroll
        for (int e = 0; e < 8; ++e) acc[e] += bf2f(vv[k][e]) * m;
    }
    const float inv = 1.0f / (float)(cnt > 1 ? cnt : 1);

    ushort8 s;
#pragma unroll
    for (int e = 0; e < 8; ++e) s[e] = f2bf(acc[e] * inv);
    *(ushort8*)(hagg + ((size_t)b * N_ + n0 + ns) * D_ + c * CW + q * 8) = s;
}

__global__ __launch_bounds__(256) void gemm_bt3(const unsigned short* __restrict__ xc,
                                                const unsigned short* __restrict__ hagg,
                                                const unsigned short* __restrict__ Bm,
                                                const float* __restrict__ bias,
                                                float* __restrict__ out) {
    __shared__ unsigned short As[64 * 32];
    __shared__ unsigned short Bs[256 * 32];

    const int tid    = threadIdx.x;
    const int w      = tid >> 6;
    const int lane   = tid & 63;
    const int tile_m = blockIdx.x * 64;
    const int q      = lane >> 4;
    const int r16    = lane & 15;
    const int crow   = lane >> 2;
    const int kofs   = (lane & 3) * 8;

    const unsigned short* ps[4];
    const unsigned short* pa[4];
#pragma unroll
    for (int c = 0; c < 4; ++c) {
        const int m  = tile_m + c * 16 + crow;
        const int b  = (m >= N_) + (m >= 2 * N_) + (m >= 3 * N_);
        const int n  = m - b * N_;
        ps[c] = xc + ((size_t)n * B_ + b) * CW + kofs;
        pa[c] = hagg + (size_t)m * D_ + kofs;
    }

    f32x4 acc[4][4] = {};

    for (int kk = 0; kk < KDIM; kk += 32) {
        const int kidx = kk >> 5;
#pragma unroll
        for (int t = 0; t < 5; ++t) {
            const int c = w * 5 + t;
            if (c < 4) {
                const unsigned short* ga = (kk < D_)
                    ? ps[c] + (size_t)kidx * CHUNK_ELEMS
                    : pa[c] + (kk - D_);
                __builtin_amdgcn_global_load_lds(
                    (const __attribute__((address_space(1))) void*)ga,
                    (__attribute__((address_space(3))) void*)(As + c * 512),
                    16, 0, 0);
            } else {
                const int row = (c - 4) * 16 + crow;
                const unsigned short* gb = Bm + (size_t)row * KDIM + kk + kofs;
                __builtin_amdgcn_global_load_lds(
                    (const __attribute__((address_space(1))) void*)gb,
                    (__attribute__((address_space(3))) void*)(Bs + (c - 4) * 512),
                    16, 0, 0);
            }
        }
        __syncthreads();

        short8 a[4], bf[4];
#pragma unroll
        for (int i = 0; i < 4; ++i)
            a[i] = *(const short8*)(As + (i * 16 + r16) * 32 + q * 8);
#pragma unroll
        for (int j = 0; j < 4; ++j)
            bf[j] = *(const short8*)(Bs + (w * 64 + j * 16 + r16) * 32 + q * 8);

#pragma unroll
        for (int i = 0; i < 4; ++i)
#pragma unroll
            for (int j = 0; j < 4; ++j)
                acc[i][j] = __builtin_amdgcn_mfma_f32_16x16x32_bf16(a[i], bf[j], acc[i][j], 0, 0, 0);

        __syncthreads();
    }

    float bj[4];
#pragma unroll
    for (int j = 0; j < 4; ++j)
        bj[j] = bias[w * 64 + j * 16 + r16];

#pragma unroll
    for (int i = 0; i < 4; ++i) {
#pragma unroll
        for (int reg = 0; reg < 4; ++reg) {
            const int m = tile_m + i * 16 + q * 4 + reg;
            float* orow = out + (size_t)m * OUT_ + w * 64;
#pragma unroll
            for (int j = 0; j < 4; ++j) {
                float v = acc[i][j][reg] + bj[j];
                orow[j * 16 + r16] = v > 0.f ? v : 0.f;
            }
        }
    }
}

// ---------------------------------------------------------------------------
extern "C" void kernel_launch(void* const* d_in, const int* in_sizes, int n_in,
                              void* d_out, int out_size, void* d_ws, size_t ws_size,
                              hipStream_t stream) {
    const float* x     = (const float*)d_in[0];   // (4, 10000, 256) fp32
    const int*   neigh = (const int*)d_in[1];     // (10000, 16) int32
    const float* W     = (const float*)d_in[2];   // (256, 512) fp32
    const float* bias  = (const float*)d_in[3];   // (256,) fp32
    float*       out   = (float*)d_out;           // (4, 10000, 256) fp32

    unsigned short* Wb   = (unsigned short*)d_ws;         // 256*512 bf16 = 0.26 MB
    unsigned short* xc   = Wb + OUT_ * KDIM;              // 8 x 2.56 MB = 20.48 MB
    unsigned short* hagg = xc + NCH * CHUNK_ELEMS;        // 40000*256 bf16 = 20.48 MB

    void* args[] = { (void*)&x, (void*)&W, (void*)&neigh, (void*)&bias,
                     (void*)&out, (void*)&xc, (void*)&hagg, (void*)&Wb };
    hipError_t err = hipLaunchCooperativeKernel((const void*)mega,
                                                dim3(GRID), dim3(256),
                                                args, 0, stream);
    if (err != hipSuccess) {
        // Fallback: proven 3-kernel pipeline (round 9).
        prep<<<5000 + 128, 256, 0, stream>>>(x, W, xc, Wb);
        gather_agg2<<<(N_ / 16) * NCH, 256, 0, stream>>>(xc, neigh, hagg);
        gemm_bt3<<<M_ / 64, 256, 0, stream>>>(xc, hagg, Wb, bias, out);
    }
}

// Round 11
// 135.121 us; speedup vs baseline: 3.2732x; 3.2732x over previous
//
#include <hip/hip_runtime.h>
#include <hip/hip_bf16.h>
#include <stdint.h>

#define B_   4
#define N_   10000
#define K_   16
#define D_   256
#define OUT_ 256
#define KDIM 512          // 2*D
#define M_   (B_ * N_)    // 40000
#define CW   32           // cols per gather chunk (64 B rows)
#define NCH  8            // number of chunks (one per XCD)
#define CHUNK_ELEMS ((size_t)N_ * B_ * CW)   // ushorts per chunk = 1,280,000

typedef __attribute__((ext_vector_type(8))) short          short8;    // MFMA frag
typedef __attribute__((ext_vector_type(8))) unsigned short ushort8;
typedef __attribute__((ext_vector_type(4))) float          f32x4;
typedef __attribute__((ext_vector_type(4))) unsigned short ushort4_t;

__device__ inline unsigned short f2bf(float f) {
    __hip_bfloat16 h = __float2bfloat16(f);
    return *reinterpret_cast<unsigned short*>(&h);
}
__device__ inline float bf2f(unsigned short u) {
    unsigned int v = ((unsigned int)u) << 16;
    return __builtin_bit_cast(float, v);
}

// ---------------------------------------------------------------------------
// Kernel 1 (prep): blocks 0..4999 : x fp32 (B,N,D) -> xc bf16 chunk-major
//   (8 chunks)[n][b][32 cols]; chunk = 2.56 MB (fits one XCD L2).
// blocks 5000..5127 : W fp32 -> Wb bf16 (B^T layout for the GEMM).
// (Proven round 9 — unchanged.)
// ---------------------------------------------------------------------------
__global__ __launch_bounds__(256) void prep(const float* __restrict__ x,
                                            const float* __restrict__ W,
                                            unsigned short* __restrict__ xc,
                                            unsigned short* __restrict__ Wb) {
    const int t = threadIdx.x;
    if (blockIdx.x < 5000) {
        const int n  = blockIdx.x * 2 + (t >> 7);      // node
        const int b  = (t >> 5) & 3;                   // batch
        const int c0 = (t & 31) * 8;                   // col base (multiple of 8)
        const float4* xr = (const float4*)(x + ((size_t)b * N_ + n) * D_ + c0);
        float4 v0 = xr[0];
        float4 v1 = xr[1];
        ushort8 s;
        s[0] = f2bf(v0.x); s[1] = f2bf(v0.y); s[2] = f2bf(v0.z); s[3] = f2bf(v0.w);
        s[4] = f2bf(v1.x); s[5] = f2bf(v1.y); s[6] = f2bf(v1.z); s[7] = f2bf(v1.w);
        const int ch  = c0 >> 5;          // chunk 0..7
        const int col = c0 & 31;          // 0,8,16,24
        *(ushort8*)(xc + (size_t)ch * CHUNK_ELEMS + ((size_t)n * B_ + b) * CW + col) = s;
    } else {
        int g = (blockIdx.x - 5000) * 256 + t;         // 0..32767, 4 elems each
        float4 v = ((const float4*)W)[g];
        ushort4_t s;
        s.x = f2bf(v.x); s.y = f2bf(v.y); s.z = f2bf(v.z); s.w = f2bf(v.w);
        ((ushort4_t*)Wb)[g] = s;
    }
}

// ---------------------------------------------------------------------------
// Kernel 2 (gather_agg2): chunk c = blockIdx & 7 -> consecutive blocks
// round-robin XCDs; each XCD's random gathers stay inside its own 2.56-MB
// L2-resident chunk. Block: 16 nodes x 4 batches = 64 tasks; 4 lanes per
// task, 16-B loads; 16 independent gather loads per thread (deep MLP).
// (Proven round 9 — unchanged.)
// ---------------------------------------------------------------------------
__global__ __launch_bounds__(256) void gather_agg2(const unsigned short* __restrict__ xc,
                                                   const int*            __restrict__ neigh,
                                                   unsigned short*       __restrict__ hagg) {
    const int c   = blockIdx.x & 7;
    const int g   = blockIdx.x >> 3;
    const int n0  = g * 16;
    const int tid = threadIdx.x;

    __shared__ int idx_s[16 * K_];   // 256 ints
    idx_s[tid] = neigh[n0 * K_ + tid];
    __syncthreads();

    const int q  = tid & 3;          // 8-ushort col group within chunk
    const int tl = tid >> 2;         // task 0..63
    const int ns = tl >> 2;          // node_sub 0..15
    const int b  = tl & 3;           // batch

    const unsigned short* xcc = xc + (size_t)c * CHUNK_ELEMS;

    int jj[K_];
    int cnt = 0;
#pragma unroll
    for (int k = 0; k < K_; ++k) {
        jj[k] = idx_s[ns * K_ + k];
        cnt += jj[k] >= 0 ? 1 : 0;
    }

    // 16 independent 16-B gather loads
    ushort8 vv[K_];
#pragma unroll
    for (int k = 0; k < K_; ++k) {
        const int jc = jj[k] >= 0 ? jj[k] : 0;
        vv[k] = *(const ushort8*)(xcc + ((size_t)jc * B_ + b) * CW + q * 8);
    }

    float acc[8] = {0.f, 0.f, 0.f, 0.f, 0.f, 0.f, 0.f, 0.f};
#pragma unroll
    for (int k = 0; k < K_; ++k) {
        const float m = jj[k] >= 0 ? 1.f : 0.f;
#pragma unroll
        for (int e = 0; e < 8; ++e) acc[e] += bf2f(vv[k][e]) * m;
    }
    const float inv = 1.0f / (float)(cnt > 1 ? cnt : 1);

    ushort8 s;
#pragma unroll
    for (int e = 0; e < 8; ++e) s[e] = f2bf(acc[e] * inv);
    *(ushort8*)(hagg + ((size_t)b * N_ + n0 + ns) * D_ + c * CW + q * 8) = s;
}

// ---------------------------------------------------------------------------
// Kernel 3 (gemm_bt5): out[m,o] = relu( [self|agg] . Wb[o,:] + bias[o] )
// bt3 structure with the tile split in N: 64 rows x 128 cols, grid (625, 2)
// = 4.88 blocks/CU (vs bt3's 2.44) so the per-iter vmcnt(0) drain is hidden
// by twice the resident blocks. LDS 12 KB. 12 staging chunks/iter, 3 per
// wave (uniform — no wave idles). A sources per-lane scattered from xc/hagg
// (proven in bt3); B rows offset by nt*128.
// ---------------------------------------------------------------------------
__global__ __launch_bounds__(256) void gemm_bt5(const unsigned short* __restrict__ xc,
                                                const unsigned short* __restrict__ hagg,
                                                const unsigned short* __restrict__ Bm,  // Wb
                                                const float* __restrict__ bias,
                                                float* __restrict__ out) {
    __shared__ unsigned short As[64 * 32];    //  4 KB
    __shared__ unsigned short Bs[128 * 32];   //  8 KB

    const int tid    = threadIdx.x;
    const int w      = tid >> 6;
    const int lane   = tid & 63;
    const int tile_m = blockIdx.x * 64;
    const int nt     = blockIdx.y;            // col tile: cols nt*128..+128
    const int q      = lane >> 4;
    const int r16    = lane & 15;

    const int crow = lane >> 2;        // 0..15: row within a 16-row chunk
    const int kofs = (lane & 3) * 8;   // ushort offset within BK=32

    // Per-lane A source pointers (proven bt3 pattern).
    const unsigned short* ps[4];
    const unsigned short* pa[4];
#pragma unroll
    for (int c = 0; c < 4; ++c) {
        const int m  = tile_m + c * 16 + crow;
        const int b  = (m >= N_) + (m >= 2 * N_) + (m >= 3 * N_);
        const int n  = m - b * N_;
        ps[c] = xc + ((size_t)n * B_ + b) * CW + kofs;     // + kidx*CHUNK_ELEMS
        pa[c] = hagg + (size_t)m * D_ + kofs;              // + (kk-256)
    }

    f32x4 acc[4][2] = {};

    for (int kk = 0; kk < KDIM; kk += 32) {
        const int kidx = kk >> 5;
#pragma unroll
        for (int t = 0; t < 3; ++t) {
            const int c = w * 3 + t;               // chunk 0..11
            if (c < 4) {                           // A chunks: rows c*16..+16
                const unsigned short* ga = (kk < D_)
                    ? ps[c] + (size_t)kidx * CHUNK_ELEMS
                    : pa[c] + (kk - D_);
                __builtin_amdgcn_global_load_lds(
                    (const __attribute__((address_space(1))) void*)ga,
                    (__attribute__((address_space(3))) void*)(As + c * 512),
                    16, 0, 0);
            } else {                               // B chunks: rows (c-4)*16..+16
                const int row = nt * 128 + (c - 4) * 16 + crow;
                const unsigned short* gb = Bm + (size_t)row * KDIM + kk + kofs;
                __builtin_amdgcn_global_load_lds(
                    (const __attribute__((address_space(1))) void*)gb,
                    (__attribute__((address_space(3))) void*)(Bs + (c - 4) * 512),
                    16, 0, 0);
            }
        }
        __syncthreads();

        short8 a[4], bf[2];
#pragma unroll
        for (int i = 0; i < 4; ++i)
            a[i] = *(const short8*)(As + (i * 16 + r16) * 32 + q * 8);
#pragma unroll
        for (int j = 0; j < 2; ++j)
            bf[j] = *(const short8*)(Bs + (w * 32 + j * 16 + r16) * 32 + q * 8);

#pragma unroll
        for (int i = 0; i < 4; ++i)
#pragma unroll
            for (int j = 0; j < 2; ++j)
                acc[i][j] = __builtin_amdgcn_mfma_f32_16x16x32_bf16(a[i], bf[j], acc[i][j], 0, 0, 0);

        __syncthreads();
    }

    // Epilogue: bias + ReLU. 40000 = 625*64 -> no row masking needed.
    float bj[2];
#pragma unroll
    for (int j = 0; j < 2; ++j)
        bj[j] = bias[nt * 128 + w * 32 + j * 16 + r16];

#pragma unroll
    for (int i = 0; i < 4; ++i) {
#pragma unroll
        for (int reg = 0; reg < 4; ++reg) {
            const int m = tile_m + i * 16 + q * 4 + reg;
            float* orow = out + (size_t)m * OUT_ + nt * 128 + w * 32;
#pragma unroll
            for (int j = 0; j < 2; ++j) {
                float v = acc[i][j][reg] + bj[j];
                orow[j * 16 + r16] = v > 0.f ? v : 0.f;
            }
        }
    }
}

// ---------------------------------------------------------------------------
extern "C" void kernel_launch(void* const* d_in, const int* in_sizes, int n_in,
                              void* d_out, int out_size, void* d_ws, size_t ws_size,
                              hipStream_t stream) {
    const float* x     = (const float*)d_in[0];   // (4, 10000, 256) fp32
    const int*   neigh = (const int*)d_in[1];     // (10000, 16) int32
    const float* W     = (const float*)d_in[2];   // (256, 512) fp32
    const float* bias  = (const float*)d_in[3];   // (256,) fp32
    float*       out   = (float*)d_out;           // (4, 10000, 256) fp32

    unsigned short* Wb   = (unsigned short*)d_ws;         // 256*512 bf16 = 0.26 MB
    unsigned short* xc   = Wb + OUT_ * KDIM;              // 8 x 2.56 MB = 20.48 MB
    unsigned short* hagg = xc + NCH * CHUNK_ELEMS;        // 40000*256 bf16 = 20.48 MB

    prep<<<5000 + 128, 256, 0, stream>>>(x, W, xc, Wb);
    gather_agg2<<<(N_ / 16) * NCH, 256, 0, stream>>>(xc, neigh, hagg);
    gemm_bt5<<<dim3(M_ / 64, 2), 256, 0, stream>>>(xc, hagg, Wb, bias, out);
}